// Round 8
// baseline (724.470 us; speedup 1.0000x reference)
//
#include <hip/hip_runtime.h>
#include <hip/hip_bf16.h>
#include <math.h>

// Problem constants
#define N_DEST 16000   // B * D_CNT
#define KN     32      // neighbors per dest
#define HIDN   128
#define NH     4
#define SRCD   64
#define EDGED  16
#define XD     80
#define XDP    96      // XD padded to 3 K-tiles of 32
#define SNP    136     // s_sin row stride (128 + 8 pad), 272B = 17*16
#define WPB    4       // waves (= dest nodes) per block

// bf16 weight workspace layout (shorts)
#define WSB_OFF 0        // W_src padded 128 x 96
#define WKV_OFF 12288    // Wqkv rows 128..383 (K then V), 256 x 128
#define WDB_OFF 45056    // W_dest 128 x 64
#define WQB_OFF 53248    // Wqkv rows 0..127 (Q), 128 x 128
#define WOB_OFF 69632    // Wo 128 x 128
#define PREP_TOT 86016

typedef __attribute__((ext_vector_type(8))) short frag8;   // 8 bf16 (4 VGPR)
typedef __attribute__((ext_vector_type(4))) float f32x4;

// tanh-form GELU (|diff vs exact erf-gelu| <= ~2e-3)
__device__ __forceinline__ float gelu_tanh(float x) {
    float t = x * x;
    float m = fmaf(t, -0.07135481627f, -1.5957691216f);
    float e = __expf(x * m);
    return __fdividef(x, 1.0f + e);
}
__device__ __forceinline__ unsigned short f2bf(float f) {
    __hip_bfloat16 h = __float2bfloat16(f);
    union { __hip_bfloat16 h; unsigned short u; } c; c.h = h; return c.u;
}
__device__ __forceinline__ unsigned int pk2bf(float x, float y) {
    __hip_bfloat162 h2 = __float22bfloat162_rn(make_float2(x, y));
    union { __hip_bfloat162 h; unsigned int u; } c; c.h = h2; return c.u;
}
__device__ __forceinline__ float bflo(unsigned int u) {
    union { unsigned int u; float f; } c; c.u = u << 16; return c.f;
}
__device__ __forceinline__ float bfhi(unsigned int u) {
    union { unsigned int u; float f; } c; c.u = u & 0xFFFF0000u; return c.f;
}
__device__ __forceinline__ float dot8(uint4 w, float4 x0, float4 x1, float acc) {
    acc = fmaf(bflo(w.x), x0.x, acc); acc = fmaf(bfhi(w.x), x0.y, acc);
    acc = fmaf(bflo(w.y), x0.z, acc); acc = fmaf(bfhi(w.y), x0.w, acc);
    acc = fmaf(bflo(w.z), x1.x, acc); acc = fmaf(bfhi(w.z), x1.y, acc);
    acc = fmaf(bflo(w.w), x1.z, acc); acc = fmaf(bfhi(w.w), x1.w, acc);
    return acc;
}
__device__ __forceinline__ frag8 pack_frag(float4 f0, float4 f1) {
    union { frag8 f; uint4 u; } c;
    c.u.x = pk2bf(f0.x, f0.y); c.u.y = pk2bf(f0.z, f0.w);
    c.u.z = pk2bf(f1.x, f1.y); c.u.w = pk2bf(f1.z, f1.w);
    return c.f;
}
__device__ __forceinline__ frag8 zero_frag() {
    union { frag8 f; uint4 u; } c;
    c.u = make_uint4(0u, 0u, 0u, 0u);
    return c.f;
}

// ---- prep: convert all weight matrices to bf16 in d_ws ----
__global__ void prep_weights(const float* __restrict__ W_src,
                             const float* __restrict__ W_dest,
                             const float* __restrict__ Wqkv,
                             const float* __restrict__ Wo,
                             unsigned short* __restrict__ ws) {
    int i = blockIdx.x * 256 + threadIdx.x;
    if (i < WKV_OFF) {                       // W_src 128 x 96 (pad K 80->96)
        int r = i / XDP, c = i - r * XDP;
        ws[i] = f2bf(c < XD ? W_src[r * XD + c] : 0.0f);
    } else if (i < WDB_OFF) {                // Wqkv K/V rows
        int j = i - WKV_OFF;
        ws[i] = f2bf(Wqkv[128 * HIDN + j]);
    } else if (i < WQB_OFF) {                // W_dest
        ws[i] = f2bf(W_dest[i - WDB_OFF]);
    } else if (i < WOB_OFF) {                // Wqkv Q rows
        ws[i] = f2bf(Wqkv[i - WQB_OFF]);
    } else if (i < PREP_TOT) {               // Wo
        ws[i] = f2bf(Wo[i - WOB_OFF]);
    }
}

__global__ __launch_bounds__(256, 3) void fused_gat_wave(
    const float* __restrict__ src,    // (16000, 64)
    const float* __restrict__ dest,   // (16000, 64)
    const int*   __restrict__ adj,    // (32, 16000)
    const int*   __restrict__ mask,   // (16000, 32)
    const float* __restrict__ edges,  // (32, 16000, 16)
    const float* __restrict__ b_src,
    const float* __restrict__ b_dest,
    const float* __restrict__ bqkv,
    const float* __restrict__ bo,
    const float* __restrict__ ln_g,
    const float* __restrict__ ln_b,
    const unsigned short* __restrict__ ws,   // bf16 weights
    float* __restrict__ out)
{
    const int tid  = threadIdx.x;
    const int wv   = tid >> 6;        // wave id 0..3
    const int lane = tid & 63;
    const int lg   = lane >> 4;       // 0..3
    const int lm   = lane & 15;       // 0..15
    const int n    = blockIdx.x * WPB + wv;   // this wave's dest node

    const unsigned short* Wsb = ws + WSB_OFF;
    const unsigned short* Wkv = ws + WKV_OFF;
    const unsigned short* Wdb = ws + WDB_OFF;
    const unsigned short* Wqb = ws + WQB_OFF;
    const unsigned short* Wob = ws + WOB_OFF;

    // per-wave LDS slices; no cross-wave sharing -> zero __syncthreads.
    // total = 34816 + 3*2048 = 40960 B -> exactly 4 blocks/CU.
    __shared__ __align__(16) unsigned short s_sin[WPB][KN][SNP];  // 34816 B
    __shared__ __align__(16) float s_dest[WPB][HIDN];             // 2048 B
    __shared__ __align__(16) float s_attn[WPB][NH][KN];           // 2048 B
    __shared__ __align__(16) float s_ctx[WPB][HIDN];              // 2048 B

    // ---- hoisted per-lane loads ----
    const int a0 = adj[lm * N_DEST + n];          // src row for kk = lm
    const int a1 = adj[(lm + 16) * N_DEST + n];   // src row for kk = lm+16
    int mv = (lane < KN) ? mask[n * KN + lane] : 0;
    const unsigned mw = (unsigned)__ballot(mv != 0);   // bit kk => masked out

    // ---------------- phase A: dest_in (gelu) ----------------
    {
        const float* drow = dest + (size_t)n * SRCD;   // wave-uniform
        float da0 = b_dest[lane], da1 = b_dest[lane + 64];
        #pragma unroll
        for (int c = 0; c < 8; ++c) {
            float4 x0 = *(const float4*)(drow + c * 8);
            float4 x1 = *(const float4*)(drow + c * 8 + 4);
            uint4 w0 = *(const uint4*)(Wdb + (size_t)lane * SRCD + c * 8);
            uint4 w1 = *(const uint4*)(Wdb + (size_t)(lane + 64) * SRCD + c * 8);
            da0 = dot8(w0, x0, x1, da0);
            da1 = dot8(w1, x0, x1, da1);
        }
        s_dest[wv][lane]      = gelu_tanh(da0);
        s_dest[wv][lane + 64] = gelu_tanh(da1);
    }
    __builtin_amdgcn_wave_barrier();

    // ---------------- phase B: q projection -> registers ----------------
    float q_r0, q_r1;     // q[lane], q[lane+64] (pre-scaled)
    {
        float qa0 = bqkv[lane], qa1 = bqkv[lane + 64];
        #pragma unroll
        for (int c = 0; c < 16; ++c) {
            float4 x0 = *(const float4*)&s_dest[wv][c * 8];
            float4 x1 = *(const float4*)&s_dest[wv][c * 8 + 4];
            uint4 w0 = *(const uint4*)(Wqb + (size_t)lane * HIDN + c * 8);
            uint4 w1 = *(const uint4*)(Wqb + (size_t)(lane + 64) * HIDN + c * 8);
            qa0 = dot8(w0, x0, x1, qa0);
            qa1 = dot8(w1, x0, x1, qa1);
        }
        q_r0 = qa0 * 0.17677669529663688110f;  // 1/sqrt(32)
        q_r1 = qa1 * 0.17677669529663688110f;
    }

    // ---------------- phase C: GEMM-D (32 x 96 @ 96 x 128) -> gelu -> s_sin ----
    {
        f32x4 accD[2][8];
        #pragma unroll
        for (int ct = 0; ct < 8; ++ct) {
            float bias = b_src[ct * 16 + lm];
            accD[0][ct] = (f32x4){bias, bias, bias, bias};
            accD[1][ct] = (f32x4){bias, bias, bias, bias};
        }
        #pragma unroll
        for (int kt = 0; kt < 3; ++kt) {
            frag8 a[2];
            if (kt < 2) {
                const int c0 = kt * 32 + lg * 8;
                if (a0) {
                    const float4* p = (const float4*)(src + (size_t)(a0 - 1) * SRCD + c0);
                    a[0] = pack_frag(p[0], p[1]);
                } else a[0] = zero_frag();
                if (a1) {
                    const float4* p = (const float4*)(src + (size_t)(a1 - 1) * SRCD + c0);
                    a[1] = pack_frag(p[0], p[1]);
                } else a[1] = zero_frag();
            } else {
                if (lg < 2) {   // x-cols 64..79 = edges 0..15
                    const float4* p0 = (const float4*)(edges + ((size_t)lm * N_DEST + n) * EDGED + lg * 8);
                    const float4* p1 = (const float4*)(edges + ((size_t)(lm + 16) * N_DEST + n) * EDGED + lg * 8);
                    a[0] = pack_frag(p0[0], p0[1]);
                    a[1] = pack_frag(p1[0], p1[1]);
                } else {        // x-cols 80..95 = zero pad
                    a[0] = zero_frag(); a[1] = zero_frag();
                }
            }
            #pragma unroll
            for (int ct = 0; ct < 8; ++ct) {
                frag8 b = *(const frag8*)(Wsb + (size_t)(ct * 16 + lm) * XDP + kt * 32 + lg * 8);
                accD[0][ct] = __builtin_amdgcn_mfma_f32_16x16x32_bf16(a[0], b, accD[0][ct], 0, 0, 0);
                accD[1][ct] = __builtin_amdgcn_mfma_f32_16x16x32_bf16(a[1], b, accD[1][ct], 0, 0, 0);
            }
        }
        #pragma unroll
        for (int r = 0; r < 2; ++r)
            #pragma unroll
            for (int ct = 0; ct < 8; ++ct)
                #pragma unroll
                for (int e = 0; e < 4; ++e)
                    s_sin[wv][r * 16 + lg * 4 + e][ct * 16 + lm] =
                        f2bf(gelu_tanh(accD[r][ct][e]));
    }
    __builtin_amdgcn_wave_barrier();

    // ---------------- phase D: GEMM-E in 4 chunks of 64 cols -------------------
    // A-fragments hoisted once into registers (32 VGPR), reused by all 4 chunks.
    frag8 af[2][4];
    #pragma unroll
    for (int kt = 0; kt < 4; ++kt) {
        af[0][kt] = *(const frag8*)&s_sin[wv][lm][kt * 32 + lg * 8];
        af[1][kt] = *(const frag8*)&s_sin[wv][16 + lm][kt * 32 + lg * 8];
    }
    // chunks 0,1 = K features (heads 2c, 2c+1): scores -> masked softmax -> s_attn
    // chunks 2,3 = V features: PV from accumulators -> s_ctx
    #pragma unroll 1
    for (int ch = 0; ch < 4; ++ch) {
        f32x4 acc[2][4];
        #pragma unroll
        for (int ct = 0; ct < 4; ++ct) {
            float bias = bqkv[128 + ch * 64 + ct * 16 + lm];
            acc[0][ct] = (f32x4){bias, bias, bias, bias};
            acc[1][ct] = (f32x4){bias, bias, bias, bias};
        }
        #pragma unroll
        for (int kt = 0; kt < 4; ++kt) {
            #pragma unroll
            for (int ct = 0; ct < 4; ++ct) {
                frag8 b = *(const frag8*)(Wkv + (size_t)(ch * 64 + ct * 16 + lm) * HIDN + kt * 32 + lg * 8);
                acc[0][ct] = __builtin_amdgcn_mfma_f32_16x16x32_bf16(af[0][kt], b, acc[0][ct], 0, 0, 0);
                acc[1][ct] = __builtin_amdgcn_mfma_f32_16x16x32_bf16(af[1][kt], b, acc[1][ct], 0, 0, 0);
            }
        }
        if (ch < 2) {
            // scores + masked softmax for heads 2ch, 2ch+1
            const float qsrc = (ch == 0) ? q_r0 : q_r1;
            #pragma unroll
            for (int hp = 0; hp < 2; ++hp) {
                const int head = ch * 2 + hp;
                float q0 = __shfl(qsrc, hp * 32 + lm);
                float q1 = __shfl(qsrc, hp * 32 + 16 + lm);
                float vals[8];    // j = r*4+e -> kk = 16r + lg*4 + e
                #pragma unroll
                for (int r = 0; r < 2; ++r)
                    #pragma unroll
                    for (int e = 0; e < 4; ++e) {
                        float v = acc[r][2 * hp][e] * q0 + acc[r][2 * hp + 1][e] * q1;
                        v += __shfl_xor(v, 1); v += __shfl_xor(v, 2);
                        v += __shfl_xor(v, 4); v += __shfl_xor(v, 8);
                        vals[r * 4 + e] = v;
                    }
                float m8 = -1e30f;
                #pragma unroll
                for (int j = 0; j < 8; ++j) {
                    const int kk = (j >> 2) * 16 + lg * 4 + (j & 3);
                    if ((mw >> kk) & 1u) vals[j] = -1e30f;
                    m8 = fmaxf(m8, vals[j]);
                }
                m8 = fmaxf(m8, __shfl_xor(m8, 16));
                m8 = fmaxf(m8, __shfl_xor(m8, 32));
                float ex[8], s8 = 0.0f;
                #pragma unroll
                for (int j = 0; j < 8; ++j) { ex[j] = __expf(vals[j] - m8); s8 += ex[j]; }
                s8 += __shfl_xor(s8, 16); s8 += __shfl_xor(s8, 32);
                const float inv = __fdividef(1.0f, s8);
                if (lm == 0) {
                    *(float4*)&s_attn[wv][head][lg * 4] =
                        make_float4(ex[0] * inv, ex[1] * inv, ex[2] * inv, ex[3] * inv);
                    *(float4*)&s_attn[wv][head][16 + lg * 4] =
                        make_float4(ex[4] * inv, ex[5] * inv, ex[6] * inv, ex[7] * inv);
                }
            }
        } else {
            // PV: ctx[d] = sum_kk attn[h][kk] * V[kk][d]
            const int hb = (ch - 2) * 2;
            float4 at[2][2];    // [hp][r]
            #pragma unroll
            for (int hp = 0; hp < 2; ++hp)
                #pragma unroll
                for (int r = 0; r < 2; ++r)
                    at[hp][r] = *(const float4*)&s_attn[wv][hb + hp][r * 16 + lg * 4];
            #pragma unroll
            for (int ct = 0; ct < 4; ++ct) {
                const int hp = ct >> 1;
                float v = 0.0f;
                #pragma unroll
                for (int r = 0; r < 2; ++r) {
                    v = fmaf(at[hp][r].x, acc[r][ct][0], v);
                    v = fmaf(at[hp][r].y, acc[r][ct][1], v);
                    v = fmaf(at[hp][r].z, acc[r][ct][2], v);
                    v = fmaf(at[hp][r].w, acc[r][ct][3], v);
                }
                v += __shfl_xor(v, 16); v += __shfl_xor(v, 32);
                if (lg == 0) s_ctx[wv][(ch - 2) * 64 + ct * 16 + lm] = v;
            }
        }
    }
    __builtin_amdgcn_wave_barrier();

    // ---------------- phase E: out projection, x2, layernorm ------------------
    {
        float oa0 = bo[lane], oa1 = bo[lane + 64];
        #pragma unroll
        for (int c = 0; c < 16; ++c) {
            float4 x0 = *(const float4*)&s_ctx[wv][c * 8];
            float4 x1 = *(const float4*)&s_ctx[wv][c * 8 + 4];
            uint4 w0 = *(const uint4*)(Wob + (size_t)lane * HIDN + c * 8);
            uint4 w1 = *(const uint4*)(Wob + (size_t)(lane + 64) * HIDN + c * 8);
            oa0 = dot8(w0, x0, x1, oa0);
            oa1 = dot8(w1, x0, x1, oa1);
        }
        float o0 = oa0 * 2.0f, o1 = oa1 * 2.0f;
        float s = o0 + o1, ss = o0 * o0 + o1 * o1;
        #pragma unroll
        for (int off = 1; off < 64; off <<= 1) {
            s  += __shfl_xor(s, off);
            ss += __shfl_xor(ss, off);
        }
        float mu  = s * (1.0f / HIDN);
        float var = ss * (1.0f / HIDN) - mu * mu;
        float rs  = rsqrtf(var + 1e-5f);
        out[(size_t)n * HIDN + lane]      = (o0 - mu) * rs * ln_g[lane] + ln_b[lane];
        out[(size_t)n * HIDN + lane + 64] = (o1 - mu) * rs * ln_g[lane + 64] + ln_b[lane + 64];
    }
}

extern "C" void kernel_launch(void* const* d_in, const int* in_sizes, int n_in,
                              void* d_out, int out_size, void* d_ws, size_t ws_size,
                              hipStream_t stream) {
    const float* src    = (const float*)d_in[0];
    const float* dest   = (const float*)d_in[1];
    const int*   adj    = (const int*)  d_in[2];
    const int*   mask   = (const int*)  d_in[3];
    const float* edges  = (const float*)d_in[4];
    const float* W_src  = (const float*)d_in[5];
    const float* b_src  = (const float*)d_in[6];
    const float* W_dest = (const float*)d_in[7];
    const float* b_dest = (const float*)d_in[8];
    const float* Wqkv   = (const float*)d_in[9];
    const float* bqkv   = (const float*)d_in[10];
    const float* Wo     = (const float*)d_in[11];
    const float* bo     = (const float*)d_in[12];
    const float* ln_g   = (const float*)d_in[13];
    const float* ln_b   = (const float*)d_in[14];
    float* outp = (float*)d_out;

    unsigned short* ws = (unsigned short*)d_ws;
    prep_weights<<<PREP_TOT / 256, 256, 0, stream>>>(W_src, W_dest, Wqkv, Wo, ws);

    fused_gat_wave<<<N_DEST / WPB, 256, 0, stream>>>(
        src, dest, adj, mask, edges, b_src, b_dest, bqkv, bo, ln_g, ln_b,
        ws, outp);
}

// Round 9
// 420.220 us; speedup vs baseline: 1.7240x; 1.7240x over previous
//
#include <hip/hip_runtime.h>
#include <hip/hip_bf16.h>
#include <math.h>

// Problem constants
#define N_DEST 16000   // B * D_CNT
#define KN     32      // neighbors per dest
#define HIDN   128
#define NH     4
#define SRCD   64
#define EDGED  16
#define XD     80
#define XDP    96      // XD padded to 3 K-tiles of 32
#define WPB    4       // waves (= dest nodes) per block

// bf16 weight workspace layout (shorts)
#define WSB_OFF 0        // W_src padded 128 x 96
#define WKV_OFF 12288    // Wqkv rows 128..383 (K then V), 256 x 128
#define WDB_OFF 45056    // W_dest 128 x 64
#define WQB_OFF 53248    // Wqkv rows 0..127 (Q), 128 x 128
#define WOB_OFF 69632    // Wo 128 x 128
#define PREP_TOT 86016

typedef __attribute__((ext_vector_type(8))) short frag8;   // 8 bf16 (4 VGPR)
typedef __attribute__((ext_vector_type(4))) float f32x4;

// tanh-form GELU (|diff vs exact erf-gelu| <= ~2e-3)
__device__ __forceinline__ float gelu_tanh(float x) {
    float t = x * x;
    float m = fmaf(t, -0.07135481627f, -1.5957691216f);
    float e = __expf(x * m);
    return __fdividef(x, 1.0f + e);
}
__device__ __forceinline__ unsigned short f2bf(float f) {
    __hip_bfloat16 h = __float2bfloat16(f);
    union { __hip_bfloat16 h; unsigned short u; } c; c.h = h; return c.u;
}
__device__ __forceinline__ unsigned int pk2bf(float x, float y) {
    __hip_bfloat162 h2 = __float22bfloat162_rn(make_float2(x, y));
    union { __hip_bfloat162 h; unsigned int u; } c; c.h = h2; return c.u;
}
__device__ __forceinline__ float bflo(unsigned int u) {
    union { unsigned int u; float f; } c; c.u = u << 16; return c.f;
}
__device__ __forceinline__ float bfhi(unsigned int u) {
    union { unsigned int u; float f; } c; c.u = u & 0xFFFF0000u; return c.f;
}
__device__ __forceinline__ float dot8(uint4 w, float4 x0, float4 x1, float acc) {
    acc = fmaf(bflo(w.x), x0.x, acc); acc = fmaf(bfhi(w.x), x0.y, acc);
    acc = fmaf(bflo(w.y), x0.z, acc); acc = fmaf(bfhi(w.y), x0.w, acc);
    acc = fmaf(bflo(w.z), x1.x, acc); acc = fmaf(bfhi(w.z), x1.y, acc);
    acc = fmaf(bflo(w.w), x1.z, acc); acc = fmaf(bfhi(w.w), x1.w, acc);
    return acc;
}
__device__ __forceinline__ frag8 pack_frag(float4 f0, float4 f1) {
    union { frag8 f; uint4 u; } c;
    c.u.x = pk2bf(f0.x, f0.y); c.u.y = pk2bf(f0.z, f0.w);
    c.u.z = pk2bf(f1.x, f1.y); c.u.w = pk2bf(f1.z, f1.w);
    return c.f;
}
__device__ __forceinline__ frag8 zero_frag() {
    union { frag8 f; uint4 u; } c;
    c.u = make_uint4(0u, 0u, 0u, 0u);
    return c.f;
}

// ---- prep: convert all weight matrices to bf16 in d_ws ----
__global__ void prep_weights(const float* __restrict__ W_src,
                             const float* __restrict__ W_dest,
                             const float* __restrict__ Wqkv,
                             const float* __restrict__ Wo,
                             unsigned short* __restrict__ ws) {
    int i = blockIdx.x * 256 + threadIdx.x;
    if (i < WKV_OFF) {                       // W_src 128 x 96 (pad K 80->96)
        int r = i / XDP, c = i - r * XDP;
        ws[i] = f2bf(c < XD ? W_src[r * XD + c] : 0.0f);
    } else if (i < WDB_OFF) {                // Wqkv K/V rows
        int j = i - WKV_OFF;
        ws[i] = f2bf(Wqkv[128 * HIDN + j]);
    } else if (i < WQB_OFF) {                // W_dest
        ws[i] = f2bf(W_dest[i - WDB_OFF]);
    } else if (i < WOB_OFF) {                // Wqkv Q rows
        ws[i] = f2bf(Wqkv[i - WQB_OFF]);
    } else if (i < PREP_TOT) {               // Wo
        ws[i] = f2bf(Wo[i - WOB_OFF]);
    }
}

__global__ __launch_bounds__(256, 4) void fused_gat_wave(
    const float* __restrict__ src,    // (16000, 64)
    const float* __restrict__ dest,   // (16000, 64)
    const int*   __restrict__ adj,    // (32, 16000)
    const int*   __restrict__ mask,   // (16000, 32)
    const float* __restrict__ edges,  // (32, 16000, 16)
    const float* __restrict__ b_src,
    const float* __restrict__ b_dest,
    const float* __restrict__ bqkv,
    const float* __restrict__ bo,
    const float* __restrict__ ln_g,
    const float* __restrict__ ln_b,
    const unsigned short* __restrict__ ws,   // bf16 weights
    float* __restrict__ out)
{
    const int tid  = threadIdx.x;
    const int wv   = tid >> 6;        // wave id 0..3
    const int lane = tid & 63;
    const int lg   = lane >> 4;       // 0..3
    const int lm   = lane & 15;       // 0..15
    const int n    = blockIdx.x * WPB + wv;   // this wave's dest node

    const unsigned short* Wsb = ws + WSB_OFF;
    const unsigned short* Wkv = ws + WKV_OFF;
    const unsigned short* Wdb = ws + WDB_OFF;
    const unsigned short* Wqb = ws + WQB_OFF;
    const unsigned short* Wob = ws + WOB_OFF;

    // per-wave LDS slices; zero __syncthreads.
    // s_sin: stride 128 shorts (256B row), XOR-swizzled on 16B granules:
    //   byte_in_row = (col*2) ^ ((row & 7) << 4)
    // total = 32768 + 2048 + 2048 + 2048 = 38912 B -> 4 blocks/CU with 8KB slack.
    __shared__ __align__(16) unsigned short s_sin[WPB][KN][128];  // 32768 B
    __shared__ __align__(16) float s_dc[WPB][HIDN];               // dest_in, then ctx
    __shared__ __align__(16) float s_q[WPB][HIDN];                // 2048 B
    __shared__ __align__(16) float s_attn[WPB][NH][KN];           // 2048 B

    // ---- hoisted per-lane loads ----
    const int a0 = adj[lm * N_DEST + n];          // src row for kk = lm
    const int a1 = adj[(lm + 16) * N_DEST + n];   // src row for kk = lm+16
    int mv = (lane < KN) ? mask[n * KN + lane] : 0;
    const unsigned mw = (unsigned)__ballot(mv != 0);   // bit kk => masked out

    // ---------------- phase A: dest_in (gelu) -> s_dc ----------------
    {
        const float* drow = dest + (size_t)n * SRCD;   // wave-uniform
        float da0 = b_dest[lane], da1 = b_dest[lane + 64];
        #pragma unroll
        for (int c = 0; c < 8; ++c) {
            float4 x0 = *(const float4*)(drow + c * 8);
            float4 x1 = *(const float4*)(drow + c * 8 + 4);
            uint4 w0 = *(const uint4*)(Wdb + (size_t)lane * SRCD + c * 8);
            uint4 w1 = *(const uint4*)(Wdb + (size_t)(lane + 64) * SRCD + c * 8);
            da0 = dot8(w0, x0, x1, da0);
            da1 = dot8(w1, x0, x1, da1);
        }
        s_dc[wv][lane]      = gelu_tanh(da0);
        s_dc[wv][lane + 64] = gelu_tanh(da1);
    }
    __builtin_amdgcn_wave_barrier();

    // ---------------- phase B: q projection -> s_q ----------------
    {
        float qa0 = bqkv[lane], qa1 = bqkv[lane + 64];
        #pragma unroll
        for (int c = 0; c < 16; ++c) {
            float4 x0 = *(const float4*)&s_dc[wv][c * 8];
            float4 x1 = *(const float4*)&s_dc[wv][c * 8 + 4];
            uint4 w0 = *(const uint4*)(Wqb + (size_t)lane * HIDN + c * 8);
            uint4 w1 = *(const uint4*)(Wqb + (size_t)(lane + 64) * HIDN + c * 8);
            qa0 = dot8(w0, x0, x1, qa0);
            qa1 = dot8(w1, x0, x1, qa1);
        }
        s_q[wv][lane]      = qa0 * 0.17677669529663688110f;  // 1/sqrt(32)
        s_q[wv][lane + 64] = qa1 * 0.17677669529663688110f;
    }
    __builtin_amdgcn_wave_barrier();

    // ---------------- phase C: GEMM-D (32 x 96 @ 96 x 128) -> gelu -> s_sin ----
    // Two halves of 4 col-tiles each: peak accumulator = 32 regs (not 64).
    {
        frag8 aall[3][2];    // A-fragments, built once (24 VGPR, die after phase C)
        #pragma unroll
        for (int kt = 0; kt < 2; ++kt) {
            const int c0 = kt * 32 + lg * 8;
            if (a0) {
                const float4* p = (const float4*)(src + (size_t)(a0 - 1) * SRCD + c0);
                aall[kt][0] = pack_frag(p[0], p[1]);
            } else aall[kt][0] = zero_frag();
            if (a1) {
                const float4* p = (const float4*)(src + (size_t)(a1 - 1) * SRCD + c0);
                aall[kt][1] = pack_frag(p[0], p[1]);
            } else aall[kt][1] = zero_frag();
        }
        if (lg < 2) {   // x-cols 64..79 = edges 0..15
            const float4* p0 = (const float4*)(edges + ((size_t)lm * N_DEST + n) * EDGED + lg * 8);
            const float4* p1 = (const float4*)(edges + ((size_t)(lm + 16) * N_DEST + n) * EDGED + lg * 8);
            aall[2][0] = pack_frag(p0[0], p0[1]);
            aall[2][1] = pack_frag(p1[0], p1[1]);
        } else {        // x-cols 80..95 = zero pad
            aall[2][0] = zero_frag(); aall[2][1] = zero_frag();
        }

        #pragma unroll 1
        for (int half = 0; half < 2; ++half) {
            f32x4 acc[2][4];
            #pragma unroll
            for (int ct = 0; ct < 4; ++ct) {
                float bias = b_src[(half * 4 + ct) * 16 + lm];
                acc[0][ct] = (f32x4){bias, bias, bias, bias};
                acc[1][ct] = (f32x4){bias, bias, bias, bias};
            }
            #pragma unroll
            for (int kt = 0; kt < 3; ++kt) {
                #pragma unroll
                for (int ct = 0; ct < 4; ++ct) {
                    frag8 b = *(const frag8*)(Wsb + (size_t)((half * 4 + ct) * 16 + lm) * XDP + kt * 32 + lg * 8);
                    acc[0][ct] = __builtin_amdgcn_mfma_f32_16x16x32_bf16(aall[kt][0], b, acc[0][ct], 0, 0, 0);
                    acc[1][ct] = __builtin_amdgcn_mfma_f32_16x16x32_bf16(aall[kt][1], b, acc[1][ct], 0, 0, 0);
                }
            }
            // swizzled epilogue stores
            #pragma unroll
            for (int r = 0; r < 2; ++r)
                #pragma unroll
                for (int ct = 0; ct < 4; ++ct)
                    #pragma unroll
                    for (int e = 0; e < 4; ++e) {
                        const int row = r * 16 + lg * 4 + e;
                        const int cb  = ((half * 4 + ct) * 16 + lm) * 2;
                        const int byt = (cb ^ ((row & 7) << 4));
                        *(unsigned short*)((char*)&s_sin[wv][row][0] + byt) =
                            f2bf(gelu_tanh(acc[r][ct][e]));
                    }
        }
    }
    __builtin_amdgcn_wave_barrier();

    // ---------------- phase D: GEMM-E in 4 chunks of 64 cols -------------------
    // chunks 0,1 = K features (heads 2c, 2c+1): scores -> masked softmax -> s_attn
    // chunks 2,3 = V features: PV from accumulators -> s_dc (ctx; dest_in is dead)
    #pragma unroll 1
    for (int ch = 0; ch < 4; ++ch) {
        f32x4 acc[2][4];
        #pragma unroll
        for (int ct = 0; ct < 4; ++ct) {
            float bias = bqkv[128 + ch * 64 + ct * 16 + lm];
            acc[0][ct] = (f32x4){bias, bias, bias, bias};
            acc[1][ct] = (f32x4){bias, bias, bias, bias};
        }
        #pragma unroll
        for (int kt = 0; kt < 4; ++kt) {
            const int off = (kt * 64 + lg * 16) ^ ((lm & 7) << 4);
            frag8 a0f = *(const frag8*)((const char*)&s_sin[wv][lm][0] + off);
            frag8 a1f = *(const frag8*)((const char*)&s_sin[wv][16 + lm][0] + off);
            #pragma unroll
            for (int ct = 0; ct < 4; ++ct) {
                frag8 b = *(const frag8*)(Wkv + (size_t)(ch * 64 + ct * 16 + lm) * HIDN + kt * 32 + lg * 8);
                acc[0][ct] = __builtin_amdgcn_mfma_f32_16x16x32_bf16(a0f, b, acc[0][ct], 0, 0, 0);
                acc[1][ct] = __builtin_amdgcn_mfma_f32_16x16x32_bf16(a1f, b, acc[1][ct], 0, 0, 0);
            }
        }
        if (ch < 2) {
            // scores + masked softmax for heads 2ch, 2ch+1
            #pragma unroll
            for (int hp = 0; hp < 2; ++hp) {
                const int head = ch * 2 + hp;
                float q0 = s_q[wv][ch * 64 + hp * 32 + lm];
                float q1 = s_q[wv][ch * 64 + hp * 32 + 16 + lm];
                float vals[8];    // j = r*4+e -> kk = 16r + lg*4 + e
                #pragma unroll
                for (int r = 0; r < 2; ++r)
                    #pragma unroll
                    for (int e = 0; e < 4; ++e) {
                        float v = acc[r][2 * hp][e] * q0 + acc[r][2 * hp + 1][e] * q1;
                        v += __shfl_xor(v, 1); v += __shfl_xor(v, 2);
                        v += __shfl_xor(v, 4); v += __shfl_xor(v, 8);
                        vals[r * 4 + e] = v;
                    }
                float m8 = -1e30f;
                #pragma unroll
                for (int j = 0; j < 8; ++j) {
                    const int kk = (j >> 2) * 16 + lg * 4 + (j & 3);
                    if ((mw >> kk) & 1u) vals[j] = -1e30f;
                    m8 = fmaxf(m8, vals[j]);
                }
                m8 = fmaxf(m8, __shfl_xor(m8, 16));
                m8 = fmaxf(m8, __shfl_xor(m8, 32));
                float ex[8], s8 = 0.0f;
                #pragma unroll
                for (int j = 0; j < 8; ++j) { ex[j] = __expf(vals[j] - m8); s8 += ex[j]; }
                s8 += __shfl_xor(s8, 16); s8 += __shfl_xor(s8, 32);
                const float inv = __fdividef(1.0f, s8);
                if (lm == 0) {
                    *(float4*)&s_attn[wv][head][lg * 4] =
                        make_float4(ex[0] * inv, ex[1] * inv, ex[2] * inv, ex[3] * inv);
                    *(float4*)&s_attn[wv][head][16 + lg * 4] =
                        make_float4(ex[4] * inv, ex[5] * inv, ex[6] * inv, ex[7] * inv);
                }
            }
        } else {
            // PV: ctx[d] = sum_kk attn[h][kk] * V[kk][d]  -> s_dc
            const int hb = (ch - 2) * 2;
            float4 at[2][2];    // [hp][r]
            #pragma unroll
            for (int hp = 0; hp < 2; ++hp)
                #pragma unroll
                for (int r = 0; r < 2; ++r)
                    at[hp][r] = *(const float4*)&s_attn[wv][hb + hp][r * 16 + lg * 4];
            #pragma unroll
            for (int ct = 0; ct < 4; ++ct) {
                const int hp = ct >> 1;
                float v = 0.0f;
                #pragma unroll
                for (int r = 0; r < 2; ++r) {
                    v = fmaf(at[hp][r].x, acc[r][ct][0], v);
                    v = fmaf(at[hp][r].y, acc[r][ct][1], v);
                    v = fmaf(at[hp][r].z, acc[r][ct][2], v);
                    v = fmaf(at[hp][r].w, acc[r][ct][3], v);
                }
                v += __shfl_xor(v, 16); v += __shfl_xor(v, 32);
                if (lg == 0) s_dc[wv][(ch - 2) * 64 + ct * 16 + lm] = v;
            }
        }
    }
    __builtin_amdgcn_wave_barrier();

    // ---------------- phase E: out projection, x2, layernorm ------------------
    {
        float oa0 = bo[lane], oa1 = bo[lane + 64];
        #pragma unroll
        for (int c = 0; c < 16; ++c) {
            float4 x0 = *(const float4*)&s_dc[wv][c * 8];
            float4 x1 = *(const float4*)&s_dc[wv][c * 8 + 4];
            uint4 w0 = *(const uint4*)(Wob + (size_t)lane * HIDN + c * 8);
            uint4 w1 = *(const uint4*)(Wob + (size_t)(lane + 64) * HIDN + c * 8);
            oa0 = dot8(w0, x0, x1, oa0);
            oa1 = dot8(w1, x0, x1, oa1);
        }
        float o0 = oa0 * 2.0f, o1 = oa1 * 2.0f;
        float s = o0 + o1, ss = o0 * o0 + o1 * o1;
        #pragma unroll
        for (int off = 1; off < 64; off <<= 1) {
            s  += __shfl_xor(s, off);
            ss += __shfl_xor(ss, off);
        }
        float mu  = s * (1.0f / HIDN);
        float var = ss * (1.0f / HIDN) - mu * mu;
        float rs  = rsqrtf(var + 1e-5f);
        out[(size_t)n * HIDN + lane]      = (o0 - mu) * rs * ln_g[lane] + ln_b[lane];
        out[(size_t)n * HIDN + lane + 64] = (o1 - mu) * rs * ln_g[lane + 64] + ln_b[lane + 64];
    }
}

extern "C" void kernel_launch(void* const* d_in, const int* in_sizes, int n_in,
                              void* d_out, int out_size, void* d_ws, size_t ws_size,
                              hipStream_t stream) {
    const float* src    = (const float*)d_in[0];
    const float* dest   = (const float*)d_in[1];
    const int*   adj    = (const int*)  d_in[2];
    const int*   mask   = (const int*)  d_in[3];
    const float* edges  = (const float*)d_in[4];
    const float* W_src  = (const float*)d_in[5];
    const float* b_src  = (const float*)d_in[6];
    const float* W_dest = (const float*)d_in[7];
    const float* b_dest = (const float*)d_in[8];
    const float* Wqkv   = (const float*)d_in[9];
    const float* bqkv   = (const float*)d_in[10];
    const float* Wo     = (const float*)d_in[11];
    const float* bo     = (const float*)d_in[12];
    const float* ln_g   = (const float*)d_in[13];
    const float* ln_b   = (const float*)d_in[14];
    float* outp = (float*)d_out;

    unsigned short* ws = (unsigned short*)d_ws;
    prep_weights<<<PREP_TOT / 256, 256, 0, stream>>>(W_src, W_dest, Wqkv, Wo, ws);

    fused_gat_wave<<<N_DEST / WPB, 256, 0, stream>>>(
        src, dest, adj, mask, edges, b_src, b_dest, bqkv, bo, ln_g, ln_b,
        ws, outp);
}

// Round 10
// 334.656 us; speedup vs baseline: 2.1648x; 1.2557x over previous
//
#include <hip/hip_runtime.h>
#include <hip/hip_bf16.h>
#include <math.h>

// Problem constants
#define N_DEST 16000   // B * D_CNT
#define KN     32      // neighbors per dest
#define HIDN   128
#define NH     4
#define SRCD   64
#define EDGED  16
#define XD     80
#define XDP    96      // XD padded to 3 K-tiles of 32
#define WPB    4       // waves per block
#define NPW    2       // nodes per wave

// bf16 weight workspace layout (shorts)
#define WSB_OFF 0        // W_src padded 128 x 96
#define WKV_OFF 12288    // Wqkv rows 128..383 (K then V), 256 x 128
#define WDB_OFF 45056    // W_dest 128 x 64
#define WQB_OFF 53248    // Wqkv rows 0..127 (Q), 128 x 128
#define WOB_OFF 69632    // Wo 128 x 128
#define PREP_TOT 86016

typedef __attribute__((ext_vector_type(8))) short frag8;   // 8 bf16 (4 VGPR)
typedef __attribute__((ext_vector_type(4))) float f32x4;

// tanh-form GELU (|diff vs exact erf-gelu| <= ~2e-3)
__device__ __forceinline__ float gelu_tanh(float x) {
    float t = x * x;
    float m = fmaf(t, -0.07135481627f, -1.5957691216f);
    float e = __expf(x * m);
    return __fdividef(x, 1.0f + e);
}
__device__ __forceinline__ unsigned short f2bf(float f) {
    __hip_bfloat16 h = __float2bfloat16(f);
    union { __hip_bfloat16 h; unsigned short u; } c; c.h = h; return c.u;
}
__device__ __forceinline__ unsigned int pk2bf(float x, float y) {
    __hip_bfloat162 h2 = __float22bfloat162_rn(make_float2(x, y));
    union { __hip_bfloat162 h; unsigned int u; } c; c.h = h2; return c.u;
}
__device__ __forceinline__ float bflo(unsigned int u) {
    union { unsigned int u; float f; } c; c.u = u << 16; return c.f;
}
__device__ __forceinline__ float bfhi(unsigned int u) {
    union { unsigned int u; float f; } c; c.u = u & 0xFFFF0000u; return c.f;
}
__device__ __forceinline__ float dot8(uint4 w, float4 x0, float4 x1, float acc) {
    acc = fmaf(bflo(w.x), x0.x, acc); acc = fmaf(bfhi(w.x), x0.y, acc);
    acc = fmaf(bflo(w.y), x0.z, acc); acc = fmaf(bfhi(w.y), x0.w, acc);
    acc = fmaf(bflo(w.z), x1.x, acc); acc = fmaf(bfhi(w.z), x1.y, acc);
    acc = fmaf(bflo(w.w), x1.z, acc); acc = fmaf(bfhi(w.w), x1.w, acc);
    return acc;
}
__device__ __forceinline__ frag8 pack_frag(float4 f0, float4 f1) {
    union { frag8 f; uint4 u; } c;
    c.u.x = pk2bf(f0.x, f0.y); c.u.y = pk2bf(f0.z, f0.w);
    c.u.z = pk2bf(f1.x, f1.y); c.u.w = pk2bf(f1.z, f1.w);
    return c.f;
}
__device__ __forceinline__ frag8 zero_frag() {
    union { frag8 f; uint4 u; } c;
    c.u = make_uint4(0u, 0u, 0u, 0u);
    return c.f;
}

// ---- prep: convert all weight matrices to bf16 in d_ws ----
__global__ void prep_weights(const float* __restrict__ W_src,
                             const float* __restrict__ W_dest,
                             const float* __restrict__ Wqkv,
                             const float* __restrict__ Wo,
                             unsigned short* __restrict__ ws) {
    int i = blockIdx.x * 256 + threadIdx.x;
    if (i < WKV_OFF) {                       // W_src 128 x 96 (pad K 80->96)
        int r = i / XDP, c = i - r * XDP;
        ws[i] = f2bf(c < XD ? W_src[r * XD + c] : 0.0f);
    } else if (i < WDB_OFF) {                // Wqkv K/V rows
        int j = i - WKV_OFF;
        ws[i] = f2bf(Wqkv[128 * HIDN + j]);
    } else if (i < WQB_OFF) {                // W_dest
        ws[i] = f2bf(W_dest[i - WDB_OFF]);
    } else if (i < WOB_OFF) {                // Wqkv Q rows
        ws[i] = f2bf(Wqkv[i - WQB_OFF]);
    } else if (i < PREP_TOT) {               // Wo
        ws[i] = f2bf(Wo[i - WOB_OFF]);
    }
}

// ---- phase C body: GEMM-D for one node -> gelu -> swizzled s_sin slice ----
__device__ __forceinline__ void gemm_d_node(
    int n, int a0, int a1,
    const float* __restrict__ src, const float* __restrict__ edges,
    const float* __restrict__ b_src, const unsigned short* __restrict__ Wsb,
    unsigned short (*sinp)[128], int lg, int lm)
{
    frag8 aall[3][2];
    #pragma unroll
    for (int kt = 0; kt < 2; ++kt) {
        const int c0 = kt * 32 + lg * 8;
        if (a0) {
            const float4* p = (const float4*)(src + (size_t)(a0 - 1) * SRCD + c0);
            aall[kt][0] = pack_frag(p[0], p[1]);
        } else aall[kt][0] = zero_frag();
        if (a1) {
            const float4* p = (const float4*)(src + (size_t)(a1 - 1) * SRCD + c0);
            aall[kt][1] = pack_frag(p[0], p[1]);
        } else aall[kt][1] = zero_frag();
    }
    if (lg < 2) {   // x-cols 64..79 = edges 0..15
        const float4* p0 = (const float4*)(edges + ((size_t)lm * N_DEST + n) * EDGED + lg * 8);
        const float4* p1 = (const float4*)(edges + ((size_t)(lm + 16) * N_DEST + n) * EDGED + lg * 8);
        aall[2][0] = pack_frag(p0[0], p0[1]);
        aall[2][1] = pack_frag(p1[0], p1[1]);
    } else {        // x-cols 80..95 = zero pad
        aall[2][0] = zero_frag(); aall[2][1] = zero_frag();
    }

    #pragma unroll 1
    for (int half = 0; half < 2; ++half) {
        f32x4 acc[2][4];
        #pragma unroll
        for (int ct = 0; ct < 4; ++ct) {
            float bias = b_src[(half * 4 + ct) * 16 + lm];
            acc[0][ct] = (f32x4){bias, bias, bias, bias};
            acc[1][ct] = (f32x4){bias, bias, bias, bias};
        }
        #pragma unroll
        for (int kt = 0; kt < 3; ++kt) {
            #pragma unroll
            for (int ct = 0; ct < 4; ++ct) {
                frag8 b = *(const frag8*)(Wsb + (size_t)((half * 4 + ct) * 16 + lm) * XDP + kt * 32 + lg * 8);
                acc[0][ct] = __builtin_amdgcn_mfma_f32_16x16x32_bf16(aall[kt][0], b, acc[0][ct], 0, 0, 0);
                acc[1][ct] = __builtin_amdgcn_mfma_f32_16x16x32_bf16(aall[kt][1], b, acc[1][ct], 0, 0, 0);
            }
        }
        #pragma unroll
        for (int r = 0; r < 2; ++r)
            #pragma unroll
            for (int ct = 0; ct < 4; ++ct)
                #pragma unroll
                for (int e = 0; e < 4; ++e) {
                    const int row = r * 16 + lg * 4 + e;
                    const int cb  = ((half * 4 + ct) * 16 + lm) * 2;
                    const int byt = (cb ^ ((row & 7) << 4));
                    *(unsigned short*)((char*)&sinp[row][0] + byt) =
                        f2bf(gelu_tanh(acc[r][ct][e]));
                }
    }
}

// ---- softmax for one head, one node, from K-chunk accumulators ----
__device__ __forceinline__ void softmax_head(
    const f32x4 (&acc)[2][4], unsigned mw, const float* __restrict__ sq,
    float* __restrict__ attn_row, int ch, int hp, int lg, int lm)
{
    float q0 = sq[ch * 64 + hp * 32 + lm];
    float q1 = sq[ch * 64 + hp * 32 + 16 + lm];
    float vals[8];    // j = r*4+e -> kk = 16r + lg*4 + e
    #pragma unroll
    for (int r = 0; r < 2; ++r)
        #pragma unroll
        for (int e = 0; e < 4; ++e) {
            float v = acc[r][2 * hp][e] * q0 + acc[r][2 * hp + 1][e] * q1;
            v += __shfl_xor(v, 1); v += __shfl_xor(v, 2);
            v += __shfl_xor(v, 4); v += __shfl_xor(v, 8);
            vals[r * 4 + e] = v;
        }
    float m8 = -1e30f;
    #pragma unroll
    for (int j = 0; j < 8; ++j) {
        const int kk = (j >> 2) * 16 + lg * 4 + (j & 3);
        if ((mw >> kk) & 1u) vals[j] = -1e30f;
        m8 = fmaxf(m8, vals[j]);
    }
    m8 = fmaxf(m8, __shfl_xor(m8, 16));
    m8 = fmaxf(m8, __shfl_xor(m8, 32));
    float ex[8], s8 = 0.0f;
    #pragma unroll
    for (int j = 0; j < 8; ++j) { ex[j] = __expf(vals[j] - m8); s8 += ex[j]; }
    s8 += __shfl_xor(s8, 16); s8 += __shfl_xor(s8, 32);
    const float inv = __fdividef(1.0f, s8);
    if (lm == 0) {
        *(float4*)&attn_row[lg * 4] =
            make_float4(ex[0] * inv, ex[1] * inv, ex[2] * inv, ex[3] * inv);
        *(float4*)&attn_row[16 + lg * 4] =
            make_float4(ex[4] * inv, ex[5] * inv, ex[6] * inv, ex[7] * inv);
    }
}

// ---- PV for one node from V-chunk accumulators ----
__device__ __forceinline__ void pv_node(
    const f32x4 (&acc)[2][4], const float (*attn)[KN],
    float* __restrict__ ctx, int ch, int lg, int lm)
{
    const int hb = (ch - 2) * 2;
    float4 at[2][2];    // [hp][r]
    #pragma unroll
    for (int hp = 0; hp < 2; ++hp)
        #pragma unroll
        for (int r = 0; r < 2; ++r)
            at[hp][r] = *(const float4*)&attn[hb + hp][r * 16 + lg * 4];
    #pragma unroll
    for (int ct = 0; ct < 4; ++ct) {
        const int hp = ct >> 1;
        float v = 0.0f;
        #pragma unroll
        for (int r = 0; r < 2; ++r) {
            v = fmaf(at[hp][r].x, acc[r][ct][0], v);
            v = fmaf(at[hp][r].y, acc[r][ct][1], v);
            v = fmaf(at[hp][r].z, acc[r][ct][2], v);
            v = fmaf(at[hp][r].w, acc[r][ct][3], v);
        }
        v += __shfl_xor(v, 16); v += __shfl_xor(v, 32);
        if (lg == 0) ctx[(ch - 2) * 64 + ct * 16 + lm] = v;
    }
}

__global__ __launch_bounds__(256, 2) void fused_gat_wave(
    const float* __restrict__ src,    // (16000, 64)
    const float* __restrict__ dest,   // (16000, 64)
    const int*   __restrict__ adj,    // (32, 16000)
    const int*   __restrict__ mask,   // (16000, 32)
    const float* __restrict__ edges,  // (32, 16000, 16)
    const float* __restrict__ b_src,
    const float* __restrict__ b_dest,
    const float* __restrict__ bqkv,
    const float* __restrict__ bo,
    const float* __restrict__ ln_g,
    const float* __restrict__ ln_b,
    const unsigned short* __restrict__ ws,   // bf16 weights
    float* __restrict__ out)
{
    const int tid  = threadIdx.x;
    const int wv   = tid >> 6;        // wave id 0..3
    const int lane = tid & 63;
    const int lg   = lane >> 4;       // 0..3
    const int lm   = lane & 15;       // 0..15
    const int n0   = (blockIdx.x * WPB + wv) * NPW;   // nodes n0, n0+1

    const unsigned short* Wsb = ws + WSB_OFF;
    const unsigned short* Wkv = ws + WKV_OFF;
    const unsigned short* Wdb = ws + WDB_OFF;
    const unsigned short* Wqb = ws + WQB_OFF;
    const unsigned short* Wob = ws + WOB_OFF;

    // per-wave LDS slices; zero __syncthreads.
    // total = 65536 + 4096*3 = 77824 B -> 2 blocks/CU.
    __shared__ __align__(16) unsigned short s_sin[WPB][NPW][KN][128]; // 65536 B
    __shared__ __align__(16) float s_dc[WPB][NPW][HIDN];              // dest_in then ctx
    __shared__ __align__(16) float s_q[WPB][NPW][HIDN];
    __shared__ __align__(16) float s_attn[WPB][NPW][NH][KN];

    // ---- hoisted per-lane loads ----
    const int a00 = adj[lm * N_DEST + n0];
    const int a01 = adj[(lm + 16) * N_DEST + n0];
    const int a10 = adj[lm * N_DEST + n0 + 1];
    const int a11 = adj[(lm + 16) * N_DEST + n0 + 1];
    // mask rows for n0 (lanes 0..31) and n0+1 (lanes 32..63) are contiguous
    const int mv = mask[n0 * KN + lane];
    const unsigned long long bal = __ballot(mv != 0);
    const unsigned mw0 = (unsigned)bal;
    const unsigned mw1 = (unsigned)(bal >> 32);

    // ---------------- phase A: dest_in (gelu) for both nodes ----------------
    {
        const float* dr0 = dest + (size_t)n0 * SRCD;
        const float* dr1 = dest + (size_t)(n0 + 1) * SRCD;
        float bd0 = b_dest[lane], bd1 = b_dest[lane + 64];
        float da0 = bd0, da1 = bd1, db0 = bd0, db1 = bd1;
        #pragma unroll
        for (int c = 0; c < 8; ++c) {
            float4 xa0 = *(const float4*)(dr0 + c * 8);
            float4 xa1 = *(const float4*)(dr0 + c * 8 + 4);
            float4 xb0 = *(const float4*)(dr1 + c * 8);
            float4 xb1 = *(const float4*)(dr1 + c * 8 + 4);
            uint4 w0 = *(const uint4*)(Wdb + (size_t)lane * SRCD + c * 8);
            uint4 w1 = *(const uint4*)(Wdb + (size_t)(lane + 64) * SRCD + c * 8);
            da0 = dot8(w0, xa0, xa1, da0); da1 = dot8(w1, xa0, xa1, da1);
            db0 = dot8(w0, xb0, xb1, db0); db1 = dot8(w1, xb0, xb1, db1);
        }
        s_dc[wv][0][lane]      = gelu_tanh(da0);
        s_dc[wv][0][lane + 64] = gelu_tanh(da1);
        s_dc[wv][1][lane]      = gelu_tanh(db0);
        s_dc[wv][1][lane + 64] = gelu_tanh(db1);
    }
    __builtin_amdgcn_wave_barrier();

    // ---------------- phase B: q projection for both nodes ----------------
    {
        float bq0 = bqkv[lane], bq1 = bqkv[lane + 64];
        float qa0 = bq0, qa1 = bq1, qb0 = bq0, qb1 = bq1;
        #pragma unroll
        for (int c = 0; c < 16; ++c) {
            float4 xa0 = *(const float4*)&s_dc[wv][0][c * 8];
            float4 xa1 = *(const float4*)&s_dc[wv][0][c * 8 + 4];
            float4 xb0 = *(const float4*)&s_dc[wv][1][c * 8];
            float4 xb1 = *(const float4*)&s_dc[wv][1][c * 8 + 4];
            uint4 w0 = *(const uint4*)(Wqb + (size_t)lane * HIDN + c * 8);
            uint4 w1 = *(const uint4*)(Wqb + (size_t)(lane + 64) * HIDN + c * 8);
            qa0 = dot8(w0, xa0, xa1, qa0); qa1 = dot8(w1, xa0, xa1, qa1);
            qb0 = dot8(w0, xb0, xb1, qb0); qb1 = dot8(w1, xb0, xb1, qb1);
        }
        const float sc = 0.17677669529663688110f;   // 1/sqrt(32)
        s_q[wv][0][lane]      = qa0 * sc;
        s_q[wv][0][lane + 64] = qa1 * sc;
        s_q[wv][1][lane]      = qb0 * sc;
        s_q[wv][1][lane + 64] = qb1 * sc;
    }
    __builtin_amdgcn_wave_barrier();

    // ---------------- phase C: GEMM-D per node ----------------
    gemm_d_node(n0,     a00, a01, src, edges, b_src, Wsb, s_sin[wv][0], lg, lm);
    gemm_d_node(n0 + 1, a10, a11, src, edges, b_src, Wsb, s_sin[wv][1], lg, lm);
    __builtin_amdgcn_wave_barrier();

    // ---------------- phase D: GEMM-E, B-frags shared by both nodes ----------
    #pragma unroll 1
    for (int ch = 0; ch < 4; ++ch) {
        f32x4 ac0[2][4], ac1[2][4];
        #pragma unroll
        for (int ct = 0; ct < 4; ++ct) {
            float bias = bqkv[128 + ch * 64 + ct * 16 + lm];
            ac0[0][ct] = (f32x4){bias, bias, bias, bias};
            ac0[1][ct] = ac0[0][ct];
            ac1[0][ct] = ac0[0][ct];
            ac1[1][ct] = ac0[0][ct];
        }
        #pragma unroll
        for (int kt = 0; kt < 4; ++kt) {
            const int off = (kt * 64 + lg * 16) ^ ((lm & 7) << 4);
            frag8 a00f = *(const frag8*)((const char*)&s_sin[wv][0][lm][0] + off);
            frag8 a01f = *(const frag8*)((const char*)&s_sin[wv][0][16 + lm][0] + off);
            frag8 a10f = *(const frag8*)((const char*)&s_sin[wv][1][lm][0] + off);
            frag8 a11f = *(const frag8*)((const char*)&s_sin[wv][1][16 + lm][0] + off);
            #pragma unroll
            for (int ct = 0; ct < 4; ++ct) {
                frag8 b = *(const frag8*)(Wkv + (size_t)(ch * 64 + ct * 16 + lm) * HIDN + kt * 32 + lg * 8);
                ac0[0][ct] = __builtin_amdgcn_mfma_f32_16x16x32_bf16(a00f, b, ac0[0][ct], 0, 0, 0);
                ac0[1][ct] = __builtin_amdgcn_mfma_f32_16x16x32_bf16(a01f, b, ac0[1][ct], 0, 0, 0);
                ac1[0][ct] = __builtin_amdgcn_mfma_f32_16x16x32_bf16(a10f, b, ac1[0][ct], 0, 0, 0);
                ac1[1][ct] = __builtin_amdgcn_mfma_f32_16x16x32_bf16(a11f, b, ac1[1][ct], 0, 0, 0);
            }
        }
        if (ch < 2) {
            #pragma unroll
            for (int hp = 0; hp < 2; ++hp) {
                const int head = ch * 2 + hp;
                softmax_head(ac0, mw0, s_q[wv][0], s_attn[wv][0][head], ch, hp, lg, lm);
                softmax_head(ac1, mw1, s_q[wv][1], s_attn[wv][1][head], ch, hp, lg, lm);
            }
        } else {
            pv_node(ac0, s_attn[wv][0], s_dc[wv][0], ch, lg, lm);
            pv_node(ac1, s_attn[wv][1], s_dc[wv][1], ch, lg, lm);
        }
    }
    __builtin_amdgcn_wave_barrier();

    // ---------------- phase E: out projection, x2, layernorm, both nodes ------
    {
        float bo0 = bo[lane], bo1 = bo[lane + 64];
        float oa0 = bo0, oa1 = bo1, ob0 = bo0, ob1 = bo1;
        #pragma unroll
        for (int c = 0; c < 16; ++c) {
            float4 xa0 = *(const float4*)&s_dc[wv][0][c * 8];
            float4 xa1 = *(const float4*)&s_dc[wv][0][c * 8 + 4];
            float4 xb0 = *(const float4*)&s_dc[wv][1][c * 8];
            float4 xb1 = *(const float4*)&s_dc[wv][1][c * 8 + 4];
            uint4 w0 = *(const uint4*)(Wob + (size_t)lane * HIDN + c * 8);
            uint4 w1 = *(const uint4*)(Wob + (size_t)(lane + 64) * HIDN + c * 8);
            oa0 = dot8(w0, xa0, xa1, oa0); oa1 = dot8(w1, xa0, xa1, oa1);
            ob0 = dot8(w0, xb0, xb1, ob0); ob1 = dot8(w1, xb0, xb1, ob1);
        }
        float o00 = oa0 * 2.0f, o01 = oa1 * 2.0f;   // node0
        float o10 = ob0 * 2.0f, o11 = ob1 * 2.0f;   // node1
        float s0 = o00 + o01, ss0 = o00 * o00 + o01 * o01;
        float s1 = o10 + o11, ss1 = o10 * o10 + o11 * o11;
        #pragma unroll
        for (int off = 1; off < 64; off <<= 1) {
            s0  += __shfl_xor(s0, off);  ss0 += __shfl_xor(ss0, off);
            s1  += __shfl_xor(s1, off);  ss1 += __shfl_xor(ss1, off);
        }
        float mu0  = s0 * (1.0f / HIDN);
        float var0 = ss0 * (1.0f / HIDN) - mu0 * mu0;
        float rs0  = rsqrtf(var0 + 1e-5f);
        float mu1  = s1 * (1.0f / HIDN);
        float var1 = ss1 * (1.0f / HIDN) - mu1 * mu1;
        float rs1  = rsqrtf(var1 + 1e-5f);
        float g0 = ln_g[lane], g1 = ln_g[lane + 64];
        float t0 = ln_b[lane], t1 = ln_b[lane + 64];
        out[(size_t)n0 * HIDN + lane]            = (o00 - mu0) * rs0 * g0 + t0;
        out[(size_t)n0 * HIDN + lane + 64]       = (o01 - mu0) * rs0 * g1 + t1;
        out[(size_t)(n0 + 1) * HIDN + lane]      = (o10 - mu1) * rs1 * g0 + t0;
        out[(size_t)(n0 + 1) * HIDN + lane + 64] = (o11 - mu1) * rs1 * g1 + t1;
    }
}

extern "C" void kernel_launch(void* const* d_in, const int* in_sizes, int n_in,
                              void* d_out, int out_size, void* d_ws, size_t ws_size,
                              hipStream_t stream) {
    const float* src    = (const float*)d_in[0];
    const float* dest   = (const float*)d_in[1];
    const int*   adj    = (const int*)  d_in[2];
    const int*   mask   = (const int*)  d_in[3];
    const float* edges  = (const float*)d_in[4];
    const float* W_src  = (const float*)d_in[5];
    const float* b_src  = (const float*)d_in[6];
    const float* W_dest = (const float*)d_in[7];
    const float* b_dest = (const float*)d_in[8];
    const float* Wqkv   = (const float*)d_in[9];
    const float* bqkv   = (const float*)d_in[10];
    const float* Wo     = (const float*)d_in[11];
    const float* bo     = (const float*)d_in[12];
    const float* ln_g   = (const float*)d_in[13];
    const float* ln_b   = (const float*)d_in[14];
    float* outp = (float*)d_out;

    unsigned short* ws = (unsigned short*)d_ws;
    prep_weights<<<PREP_TOT / 256, 256, 0, stream>>>(W_src, W_dest, Wqkv, Wo, ws);

    fused_gat_wave<<<N_DEST / (WPB * NPW), 256, 0, stream>>>(
        src, dest, adj, mask, edges, b_src, b_dest, bqkv, bo, ln_g, ln_b,
        ws, outp);
}